// Round 13
// baseline (707.276 us; speedup 1.0000x reference)
//
#include <hip/hip_runtime.h>
#include <math.h>

#define NH 16
#define HD 64
#define DIM 1024
#define QKV_DIM 3072
#define MAXLEN 2048
#define TOTAL 5120

typedef unsigned short ushort_t;
typedef unsigned int uint_t;
typedef __attribute__((ext_vector_type(8))) short bf16x8;
typedef __attribute__((ext_vector_type(8))) unsigned short ushort8;
typedef __attribute__((ext_vector_type(4))) float f32x4;

// hardcoded problem constants (fixed by reference setup)
__device__ __constant__ int g_cu[5]  = {0, 2048, 3584, 4608, 5120};
__device__ __constant__ int g_seq[4] = {2048, 1536, 1024, 512};

// ---------------------------------------------------------------------------
// fp32 -> (hi, lo) bf16 pair. x ~= bf2f(hi)+bf2f(lo), |err| ~ 2^-17 |x|
// ---------------------------------------------------------------------------
__device__ inline ushort_t f2bf(float f) {
    uint_t u = __float_as_uint(f);
    uint_t r = u + 0x7FFFu + ((u >> 16) & 1u);   // RNE
    return (ushort_t)(r >> 16);
}
__device__ inline float bf2f(ushort_t h) { return __uint_as_float(((uint_t)h) << 16); }

__global__ __launch_bounds__(256) void split_bf16(const float* __restrict__ x,
                                                  ushort_t* __restrict__ hi,
                                                  ushort_t* __restrict__ lo, int n4) {
    int i = blockIdx.x * 256 + threadIdx.x;
    if (i >= n4) return;
    float4 v = ((const float4*)x)[i];
    ushort_t h0 = f2bf(v.x), h1 = f2bf(v.y), h2 = f2bf(v.z), h3 = f2bf(v.w);
    ushort_t l0 = f2bf(v.x - bf2f(h0));
    ushort_t l1 = f2bf(v.y - bf2f(h1));
    ushort_t l2 = f2bf(v.z - bf2f(h2));
    ushort_t l3 = f2bf(v.w - bf2f(h3));
    ushort4 hv = {h0, h1, h2, h3};
    ushort4 lv = {l0, l1, l2, l3};
    ((ushort4*)hi)[i] = hv;
    ((ushort4*)lo)[i] = lv;
}

// ---------------------------------------------------------------------------
// Split-bf16 MFMA GEMM (verified round 10/11): C = A * B^T.
// ---------------------------------------------------------------------------
__global__ __launch_bounds__(256) void gemm_mfma_split(
    const ushort_t* __restrict__ Ah, const ushort_t* __restrict__ Al,
    const ushort_t* __restrict__ Bh, const ushort_t* __restrict__ Bl,
    float* __restrict__ C, int M, int N, int K) {
    __shared__ ushort_t sAh[128 * 32], sAl[128 * 32];
    __shared__ ushort_t sBh[128 * 32], sBl[128 * 32];

    const int tid = threadIdx.x;
    const int lane = tid & 63;
    const int w = tid >> 6;
    const int bm = blockIdx.y * 128, bn = blockIdx.x * 128;
    const int wm = (w >> 1) * 64, wn = (w & 1) * 64;

    f32x4 acc[4][4] = {};

    const int srow = tid >> 2;
    const int scol = (tid & 3) * 8;

    for (int k0 = 0; k0 < K; k0 += 32) {
        __syncthreads();
#pragma unroll
        for (int i = 0; i < 2; ++i) {
            int r = i * 64 + srow;
            size_t ga = (size_t)(bm + r) * K + k0 + scol;
            size_t gb = (size_t)(bn + r) * K + k0 + scol;
            int ls = r * 32 + scol;
            *(ushort8*)&sAh[ls] = *(const ushort8*)&Ah[ga];
            *(ushort8*)&sAl[ls] = *(const ushort8*)&Al[ga];
            *(ushort8*)&sBh[ls] = *(const ushort8*)&Bh[gb];
            *(ushort8*)&sBl[ls] = *(const ushort8*)&Bl[gb];
        }
        __syncthreads();

        const int frow = lane & 15;
        const int fk = (lane >> 4) * 8;
        bf16x8 ah[4], al[4], bh[4], bl[4];
#pragma unroll
        for (int t = 0; t < 4; ++t) {
            int ar = (wm + t * 16 + frow) * 32 + fk;
            int br = (wn + t * 16 + frow) * 32 + fk;
            ah[t] = *(const bf16x8*)&sAh[ar];
            al[t] = *(const bf16x8*)&sAl[ar];
            bh[t] = *(const bf16x8*)&sBh[br];
            bl[t] = *(const bf16x8*)&sBl[br];
        }
#pragma unroll
        for (int mt = 0; mt < 4; ++mt)
#pragma unroll
            for (int nt = 0; nt < 4; ++nt) {
                acc[mt][nt] = __builtin_amdgcn_mfma_f32_16x16x32_bf16(ah[mt], bh[nt], acc[mt][nt], 0, 0, 0);
                acc[mt][nt] = __builtin_amdgcn_mfma_f32_16x16x32_bf16(ah[mt], bl[nt], acc[mt][nt], 0, 0, 0);
                acc[mt][nt] = __builtin_amdgcn_mfma_f32_16x16x32_bf16(al[mt], bh[nt], acc[mt][nt], 0, 0, 0);
            }
    }

    const int crow0 = (lane >> 4) * 4;
    const int ccol = lane & 15;
#pragma unroll
    for (int mt = 0; mt < 4; ++mt)
#pragma unroll
        for (int nt = 0; nt < 4; ++nt) {
            size_t rbase = (size_t)(bm + wm + mt * 16 + crow0) * N + bn + wn + nt * 16 + ccol;
#pragma unroll
            for (int r = 0; r < 4; ++r)
                C[rbase + (size_t)r * N] = acc[mt][nt][r];
        }
}

// ---------------------------------------------------------------------------
// Pre-pass: K rope+split -> kh/kl [token][NH*64]; V split+transpose ->
// vth/vtl [head][dim][token]. (verified round 11)
// ---------------------------------------------------------------------------
__global__ __launch_bounds__(256) void rope_split_kv(
    const float* __restrict__ qkv,
    ushort_t* __restrict__ kh, ushort_t* __restrict__ kl,
    ushort_t* __restrict__ vth, ushort_t* __restrict__ vtl) {
    __shared__ float tv[64][65];

    const int tiles_pref[5] = {0, 32, 56, 72, 80};
    int t = blockIdx.x;
    int b = 0;
    while (t >= tiles_pref[b + 1]) b++;
    const int t0 = (t - tiles_pref[b]) * 64;
    const int base = g_cu[b];
    const int h = blockIdx.y;
    const int tid = threadIdx.x;

    {
        int r = tid >> 2, jg = tid & 3;
        int tok = base + t0 + r;
        const float* kp = qkv + (size_t)tok * QKV_DIM + DIM + h * HD;
        float x1[8], x2[8];
        *(float4*)&x1[0] = *(const float4*)&kp[8 * jg + 0];
        *(float4*)&x1[4] = *(const float4*)&kp[8 * jg + 4];
        *(float4*)&x2[0] = *(const float4*)&kp[32 + 8 * jg + 0];
        *(float4*)&x2[4] = *(const float4*)&kp[32 + 8 * jg + 4];
        float pos = (float)(t0 + r);
        ushort8 h0v, l0v, h1v, l1v;
#pragma unroll
        for (int jj = 0; jj < 8; ++jj) {
            int j = 8 * jg + jj;
            float invf = powf(10000.0f, -(float)j / 32.0f);
            float sn, cs;
            sincosf(pos * invf, &sn, &cs);
            float y0 = x1[jj] * cs - x2[jj] * sn;
            float y1 = x2[jj] * cs + x1[jj] * sn;
            ushort_t hh = f2bf(y0);
            h0v[jj] = hh; l0v[jj] = f2bf(y0 - bf2f(hh));
            hh = f2bf(y1);
            h1v[jj] = hh; l1v[jj] = f2bf(y1 - bf2f(hh));
        }
        size_t o0 = (size_t)tok * DIM + h * HD + 8 * jg;
        *(ushort8*)&kh[o0] = h0v;      *(ushort8*)&kh[o0 + 32] = h1v;
        *(ushort8*)&kl[o0] = l0v;      *(ushort8*)&kl[o0 + 32] = l1v;
    }

#pragma unroll
    for (int it = 0; it < 4; ++it) {
        int item = tid + it * 256;
        int r = item >> 4, c4 = item & 15;
        *(float4*)&tv[r][c4 * 4] =
            *(const float4*)(qkv + (size_t)(base + t0 + r) * QKV_DIM + 2 * DIM + h * HD + c4 * 4);
    }
    __syncthreads();
#pragma unroll
    for (int it = 0; it < 2; ++it) {
        int chunk = tid + it * 256;
        int dd = chunk >> 3, tb = chunk & 7;
        ushort8 vh, vl;
#pragma unroll
        for (int i = 0; i < 8; ++i) {
            float f = tv[tb * 8 + i][dd];
            ushort_t hh = f2bf(f);
            vh[i] = hh; vl[i] = f2bf(f - bf2f(hh));
        }
        size_t off = (size_t)(h * HD + dd) * TOTAL + base + t0 + tb * 8;
        *(ushort8*)&vth[off] = vh;
        *(ushort8*)&vtl[off] = vl;
    }
}

// ---------------------------------------------------------------------------
// Attention v7: split-bf16 MFMA flash attention, latency-optimized.
// Changes vs v6 (357us, all pipes <35% => latency-bound):
//  - QBLK=128: 512 thr / 8 waves per block; wave owns 16 q-rows; K/V staging
//    per wave halves; K/V global re-reads halve; 16 waves/CU (2 blk x 8).
//  - T14 reg-staged prefetch: next tile's 4 global loads issued right after
//    barrier B, so the compiler's vmcnt-drain at barrier A lands after a full
//    compute phase (load latency hidden).
//  - T13 defer-max: fast path checks __all(lane_max <= m+8) with ZERO shfls;
//    full shfl max-reduce + rescale only when the running max grows.
//  - Deferred denominator: per-lane partial d, one shfl-reduce at kernel end
//    (removes 4 shfl-sums per row per tile).
//  - P LDS restride 72->64 ushorts + XOR-slot swizzle (same scheme as K/V):
//    conflict-free writes and b128 reads; P buffer 36.8->32 KB; LDS = 64 KB.
//  - XCD-chunked block swizzle (640 blocks, 80 per XCD chunk) for K/V L2 hits.
// ---------------------------------------------------------------------------
__global__ __launch_bounds__(512, 4) void attn_mfma(
    const float* __restrict__ qkv,
    const ushort_t* __restrict__ kh, const ushort_t* __restrict__ kl,
    const ushort_t* __restrict__ vth, const ushort_t* __restrict__ vtl,
    float* __restrict__ attnb) {
    __shared__ ushort_t sKh[64 * 64], sKl[64 * 64];   // row = key, 8 swz slots
    __shared__ ushort_t sVh[64 * 64], sVl[64 * 64];   // row = dim, 8 swz slots
    __shared__ ushort_t sPh[8][16 * 64], sPl[8][16 * 64];  // per-wave P, swz

    // --- block decode with XCD chunking (640 = 8 XCDs x 80) ---
    int fid = blockIdx.x;
    fid = (fid & 7) * 80 + (fid >> 3);
    const int h = fid / 40;
    int t = fid % 40;
    const int tiles_pref[5] = {0, 16, 28, 36, 40};
    int b = 0;
    while (t >= tiles_pref[b + 1]) b++;
    const int qstart = (t - tiles_pref[b]) * 128;
    const int L = g_seq[b];
    const int base = g_cu[b];

    const int tid = threadIdx.x;
    const int lane = tid & 63;
    const int w = tid >> 6;      // wave 0..7: owns q-rows 16w..16w+15
    const int c = lane & 15;     // fragment row/col lane index
    const int g = lane >> 4;     // fragment k-group

    // staging role: wave pair (w>>1) -> array, (w&1) -> row half
    const int arr = w >> 1;      // 0 Kh, 1 Kl, 2 Vh, 3 Vl
    const int half = w & 1;
    const int l3 = lane >> 3;    // 0..7
    const int sl = lane & 7;     // LDS slot
    const int gb = sl ^ l3;      // swizzled global block (constant per lane)
    const ushort_t* gsrc = arr == 0 ? kh : arr == 1 ? kl : arr == 2 ? vth : vtl;
    ushort_t* ldst = arr == 0 ? sKh : arr == 1 ? sKl : arr == 2 ? sVh : sVl;

    // ---- Q: rope + scale + split into A-fragments (registers) ----
    const float SCALE = 0.125f * 1.44269504088896f;  // 1/sqrt(64) * log2(e)
    const int qrow = qstart + 16 * w + c;            // within-batch position
    const float* qp = qkv + (size_t)(base + qrow) * QKV_DIM + h * HD;
    float x1[8], x2[8];
    *(float4*)&x1[0] = *(const float4*)&qp[8 * g + 0];
    *(float4*)&x1[4] = *(const float4*)&qp[8 * g + 4];
    *(float4*)&x2[0] = *(const float4*)&qp[32 + 8 * g + 0];
    *(float4*)&x2[4] = *(const float4*)&qp[32 + 8 * g + 4];
    bf16x8 qh0, ql0, qh1, ql1;
#pragma unroll
    for (int jj = 0; jj < 8; ++jj) {
        int j = 8 * g + jj;
        float invf = powf(10000.0f, -(float)j / 32.0f);
        float sn, cs;
        sincosf((float)qrow * invf, &sn, &cs);
        float y0 = (x1[jj] * cs - x2[jj] * sn) * SCALE;
        float y1 = (x2[jj] * cs + x1[jj] * sn) * SCALE;
        ushort_t hh = f2bf(y0);
        qh0[jj] = (short)hh; ql0[jj] = (short)f2bf(y0 - bf2f(hh));
        hh = f2bf(y1);
        qh1[jj] = (short)hh; ql1[jj] = (short)f2bf(y1 - bf2f(hh));
    }

    f32x4 o[4] = {};
    float m[4] = {-1e30f, -1e30f, -1e30f, -1e30f};
    float dp[4] = {};
    ushort8 pre[4];

    const int ntiles = L >> 6;
    // prologue: prefetch tile 0
#pragma unroll
    for (int it = 0; it < 4; ++it) {
        int rr = half * 32 + it * 8 + l3;
        size_t src = (arr < 2) ? ((size_t)(base + rr) * DIM + h * HD + 8 * gb)
                               : ((size_t)(h * HD + rr) * TOTAL + base + 8 * gb);
        pre[it] = *(const ushort8*)&gsrc[src];
    }

    for (int kt = 0; kt < ntiles; ++kt) {
        __syncthreads();  // A: prev compute done; drains vmcnt (pre ready)
        // ---- write prefetched tile to LDS ----
#pragma unroll
        for (int it = 0; it < 4; ++it) {
            int rr = half * 32 + it * 8 + l3;
            *(ushort8*)&ldst[rr * 64 + 8 * sl] = pre[it];
        }
        __syncthreads();  // B: staged tile visible

        // ---- issue next tile's loads (latency hides under compute) ----
        if (kt + 1 < ntiles) {
            const int k1 = (kt + 1) << 6;
#pragma unroll
            for (int it = 0; it < 4; ++it) {
                int rr = half * 32 + it * 8 + l3;
                size_t src = (arr < 2)
                    ? ((size_t)(base + k1 + rr) * DIM + h * HD + 8 * gb)
                    : ((size_t)(h * HD + rr) * TOTAL + base + k1 + 8 * gb);
                pre[it] = *(const ushort8*)&gsrc[src];
            }
        }

        // ---- QK^T: S[16q][64key] ----
        f32x4 sf[4] = {};
#pragma unroll
        for (int f = 0; f < 4; ++f) {
#pragma unroll
            for (int ks = 0; ks < 2; ++ks) {
                int off = (16 * f + c) * 64 + 8 * ((4 * ks + g) ^ (c & 7));
                bf16x8 bh = *(const bf16x8*)&sKh[off];
                bf16x8 bl = *(const bf16x8*)&sKl[off];
                bf16x8 qh = ks ? qh1 : qh0;
                bf16x8 ql = ks ? ql1 : ql0;
                sf[f] = __builtin_amdgcn_mfma_f32_16x16x32_bf16(qh, bh, sf[f], 0, 0, 0);
                sf[f] = __builtin_amdgcn_mfma_f32_16x16x32_bf16(qh, bl, sf[f], 0, 0, 0);
                sf[f] = __builtin_amdgcn_mfma_f32_16x16x32_bf16(ql, bh, sf[f], 0, 0, 0);
            }
        }

        // ---- online softmax, defer-max fast path, per-lane partial d ----
#pragma unroll
        for (int r = 0; r < 4; ++r) {
            float plm = fmaxf(fmaxf(sf[0][r], sf[1][r]), fmaxf(sf[2][r], sf[3][r]));
            if (!__all(plm <= m[r] + 8.0f)) {
                float rm = plm;
                rm = fmaxf(rm, __shfl_xor(rm, 1));
                rm = fmaxf(rm, __shfl_xor(rm, 2));
                rm = fmaxf(rm, __shfl_xor(rm, 4));
                rm = fmaxf(rm, __shfl_xor(rm, 8));
                float mn = fmaxf(m[r], rm);
                float corr = exp2f(m[r] - mn);
                m[r] = mn;
                dp[r] *= corr;
                o[0][r] *= corr; o[1][r] *= corr; o[2][r] *= corr; o[3][r] *= corr;
            }
            float p0 = exp2f(sf[0][r] - m[r]);
            float p1 = exp2f(sf[1][r] - m[r]);
            float p2 = exp2f(sf[2][r] - m[r]);
            float p3 = exp2f(sf[3][r] - m[r]);
            dp[r] += (p0 + p1) + (p2 + p3);
            float pv[4] = {p0, p1, p2, p3};
            int rbase = (4 * g + r) * 64 + (c & 7);
            int rx = (4 * g + r) & 7;
#pragma unroll
            for (int f = 0; f < 4; ++f) {
                int addr = rbase + 8 * (((c >> 3) + 2 * f) ^ rx);
                ushort_t ph = f2bf(pv[f]);
                sPh[w][addr] = ph;
                sPl[w][addr] = f2bf(pv[f] - bf2f(ph));
            }
        }
        asm volatile("s_waitcnt lgkmcnt(0)" ::: "memory");  // P visible (wave-local)
        __builtin_amdgcn_sched_barrier(0);

        // ---- PV: O[16q][64dim] += P * V ----
#pragma unroll
        for (int ks = 0; ks < 2; ++ks) {
            int poff = c * 64 + 8 * ((4 * ks + g) ^ (c & 7));
            bf16x8 pah = *(const bf16x8*)&sPh[w][poff];
            bf16x8 pal = *(const bf16x8*)&sPl[w][poff];
#pragma unroll
            for (int fd = 0; fd < 4; ++fd) {
                int off = (16 * fd + c) * 64 + 8 * ((4 * ks + g) ^ (c & 7));
                bf16x8 vh = *(const bf16x8*)&sVh[off];
                bf16x8 vl = *(const bf16x8*)&sVl[off];
                o[fd] = __builtin_amdgcn_mfma_f32_16x16x32_bf16(pah, vh, o[fd], 0, 0, 0);
                o[fd] = __builtin_amdgcn_mfma_f32_16x16x32_bf16(pah, vl, o[fd], 0, 0, 0);
                o[fd] = __builtin_amdgcn_mfma_f32_16x16x32_bf16(pal, vh, o[fd], 0, 0, 0);
            }
        }
    }

    // ---- final: reduce per-lane d over the 16-lane c-group, pad term, write
    const int npad = MAXLEN - L;
#pragma unroll
    for (int r = 0; r < 4; ++r) {
        float dr = dp[r];
        dr += __shfl_xor(dr, 1);
        dr += __shfl_xor(dr, 2);
        dr += __shfl_xor(dr, 4);
        dr += __shfl_xor(dr, 8);
        if (npad) dr += (float)npad * exp2f(0.0f - m[r]);
        float inv = 1.0f / dr;
        int row = base + qstart + 16 * w + 4 * g + r;
        float* op = attnb + (size_t)row * DIM + h * HD;
#pragma unroll
        for (int fd = 0; fd < 4; ++fd)
            op[16 * fd + c] = o[fd][r] * inv;
    }
}

// ---------------------------------------------------------------------------
extern "C" void kernel_launch(void* const* d_in, const int* in_sizes, int n_in,
                              void* d_out, int out_size, void* d_ws, size_t ws_size,
                              hipStream_t stream) {
    const float* hidden = (const float*)d_in[0];
    const float* Wqkv = (const float*)d_in[1];
    const float* Wo = (const float*)d_in[2];
    float* out = (float*)d_out;

    const int total = in_sizes[0] / DIM;  // 5120

    // workspace layout (same footprint as rounds 10/11, which passed)
    float* qkv = (float*)d_ws;                           // total*3072 f32
    float* attnb = qkv + (size_t)total * QKV_DIM;        // total*1024 f32
    ushort_t* us = (ushort_t*)(attnb + (size_t)total * DIM);
    const size_t nh = (size_t)total * DIM;               // 5.24M
    const size_t nw = (size_t)QKV_DIM * DIM;             // 3.15M
    const size_t no = (size_t)DIM * DIM;                 // 1.05M
    ushort_t* h_hi = us;            ushort_t* h_lo = h_hi + nh;
    ushort_t* wq_hi = h_lo + nh;    ushort_t* wq_lo = wq_hi + nw;
    ushort_t* ao_hi = wq_lo + nw;   ushort_t* ao_lo = ao_hi + nh;
    ushort_t* wo_hi = ao_lo + nh;   ushort_t* wo_lo = wo_hi + no;
    // sequential-use aliases (safe on a single stream):
    ushort_t* kh  = h_hi;    // h splits dead after GEMM1
    ushort_t* kl  = h_lo;
    ushort_t* vth = wq_hi;   // wq splits dead after GEMM1
    ushort_t* vtl = ao_hi;   // read by attn; ao_hi written only after attn

    // 0) split inputs
    split_bf16<<<(int)(nh / 4 + 255) / 256, 256, 0, stream>>>(hidden, h_hi, h_lo, (int)(nh / 4));
    split_bf16<<<(int)(nw / 4 + 255) / 256, 256, 0, stream>>>(Wqkv, wq_hi, wq_lo, (int)(nw / 4));
    split_bf16<<<(int)(no / 4 + 255) / 256, 256, 0, stream>>>(Wo, wo_hi, wo_lo, (int)(no / 4));

    // 1) qkv = hidden @ Wqkv^T
    gemm_mfma_split<<<dim3(QKV_DIM / 128, total / 128), 256, 0, stream>>>(
        h_hi, h_lo, wq_hi, wq_lo, qkv, total, QKV_DIM, DIM);

    // 2) K rope+split, V split+transpose
    rope_split_kv<<<dim3(80, NH), 256, 0, stream>>>(qkv, kh, kl, vth, vtl);

    // 3) attention (MFMA, QBLK=128) -> attnb
    attn_mfma<<<640, 512, 0, stream>>>(qkv, kh, kl, vth, vtl, attnb);

    // 4) split attn output, out = attnb @ Wo^T
    split_bf16<<<(int)(nh / 4 + 255) / 256, 256, 0, stream>>>(attnb, ao_hi, ao_lo, (int)(nh / 4));
    gemm_mfma_split<<<dim3(DIM / 128, total / 128), 256, 0, stream>>>(
        ao_hi, ao_lo, wo_hi, wo_lo, out, total, DIM, DIM);
}